// Round 7
// baseline (312.294 us; speedup 1.0000x reference)
//
#include <hip/hip_runtime.h>
#include <hip/hip_bf16.h>
#include <math.h>

// (B, L, H, C) = (2, 512, 128, 25)
#define BB 2
#define LL 512
#define HH 128
#define CC 25
#define W4H (4*HH)

typedef __attribute__((ext_vector_type(4))) float    f32x4;
typedef __attribute__((ext_vector_type(8))) _Float16 half8;
typedef __attribute__((ext_vector_type(2))) _Float16 half2t;
typedef __attribute__((ext_vector_type(4))) unsigned uint4v;

#define MTILE 64    // m rows per block (4 waves x 16)
#define LPB   8     // l rows per block
#define XPH   136   // f16 LDS pitch in halves (272 B rows)

static __device__ __forceinline__ half8 habs8(half8 x) {
    uint4v u = __builtin_bit_cast(uint4v, x);
    u &= 0x7FFF7FFFu;
    return __builtin_bit_cast(half8, u);
}
static __device__ __forceinline__ half2t pkrtz(float a, float b) {
    return __builtin_bit_cast(half2t, __builtin_amdgcn_cvt_pkrtz(a, b));
}
union H4 { half2t h2[2]; unsigned long long u64; };
union H8 { half2t h2[4]; uint4v u4; half8 h8; };

// Features per (l,m): f[k], k in [0,512):
//   k<128: x1*x2 (W3) | 128<=k<256: |x1-x2| (W4) | 256<=k<384: x1 (W1) | else: x2 (W2)
// W column for feature k: (k+256) & 511.
// ws holds W fragments f16, fragment-linear: frag fid = (kk*2 + t)*64 + lane, 8 halves each.

// One-time W pack: 2048 fragments, 8 blocks x 256 threads, one frag per thread.
__global__ __launch_bounds__(256)
void wpack_kernel(const float* __restrict__ W, _Float16* __restrict__ wsWf)
{
    const int fid = blockIdx.x * 256 + threadIdx.x;   // 0..2047
    const int ln  = fid & 63;
    const int t   = (fid >> 6) & 1;
    const int kk  = fid >> 7;                          // 0..15
    const int c   = (ln & 15) + 16 * t;
    const int k0  = kk * 32 + ((ln >> 4) << 3);
    const int wc  = (k0 + 256) & 511;
    H8 h; h.u4 = (uint4v){0u, 0u, 0u, 0u};
    if (c < CC) {
        const f32x4 v0 = *(const f32x4*)(W + (size_t)c * W4H + wc);
        const f32x4 v1 = *(const f32x4*)(W + (size_t)c * W4H + wc + 4);
        h.h2[0] = pkrtz(v0[0], v0[1]);
        h.h2[1] = pkrtz(v0[2], v0[3]);
        h.h2[2] = pkrtz(v1[0], v1[1]);
        h.h2[3] = pkrtz(v1[2], v1[3]);
    }
    *(uint4v*)(wsWf + (size_t)fid * 8) = h.u4;        // contiguous 16B stores
}

__global__ __launch_bounds__(256, 4)
void biaffine_fused(const float* __restrict__ x1, const float* __restrict__ x2,
                    const _Float16* __restrict__ wsWf, const float* __restrict__ bias,
                    float* __restrict__ out)
{
    __shared__ __align__(16) _Float16 x2h[MTILE * XPH];     // 17408 B
    __shared__ __align__(16) _Float16 x1h[LPB * XPH];       //  2176 B

    const int tid = threadIdx.x;
    const int b   = blockIdx.z;
    const int l0  = blockIdx.y * LPB;
    const int m0  = blockIdx.x * MTILE;

    const int lane = tid & 63;
    const int wv   = tid >> 6;      // wave 0..3
    const int q    = lane >> 4;     // k-group 0..3
    const int cn   = lane & 15;     // A-row (m) for frags; D-col (c) for output

    // ---- stage x2 tile (64x128) and x1 rows (8x128), f32 -> f16 ----
    {
        const float* sx2 = x2 + ((size_t)b * LL + m0) * HH;
        #pragma unroll
        for (int i = 0; i < 8; ++i) {
            const int idx = i * 256 + tid;
            const int r   = idx >> 5;
            const int c4  = idx & 31;
            const f32x4 v = *(const f32x4*)(sx2 + r * HH + c4 * 4);
            H4 h;
            h.h2[0] = pkrtz(v[0], v[1]);
            h.h2[1] = pkrtz(v[2], v[3]);
            *(unsigned long long*)(&x2h[r * XPH + c4 * 4]) = h.u64;
        }
        const float* sx1 = x1 + ((size_t)b * LL + l0) * HH;
        const int r  = tid >> 5;
        const int c4 = tid & 31;
        const f32x4 v = *(const f32x4*)(sx1 + r * HH + c4 * 4);
        H4 h;
        h.h2[0] = pkrtz(v[0], v[1]);
        h.h2[1] = pkrtz(v[2], v[3]);
        *(unsigned long long*)(&x1h[r * XPH + c4 * 4]) = h.u64;
    }
    __syncthreads();

    // ---- register-cache this lane's x2 fragments ----
    const int mrowA = wv * 16 + cn;
    half8 X2f[4];
    #pragma unroll
    for (int hh = 0; hh < 4; ++hh)
        X2f[hh] = *(const half8*)(&x2h[mrowA * XPH + hh * 32 + q * 8]);

    // ---- two c-tile passes: only 16 B-frags (64 VGPR) persistent at a time ----
    for (int t = 0; t < 2; ++t) {
        half8 Bf[16];
        #pragma unroll
        for (int kk = 0; kk < 16; ++kk)
            Bf[kk] = *(const half8*)(wsWf + ((size_t)(kk * 2 + t) * 64 + lane) * 8);

        const int  cg   = cn + 16 * t;
        const bool cok  = (cg < CC);
        const float bt  = cok ? bias[cg] : 0.f;

        #pragma unroll
        for (int l = 0; l < LPB; ++l) {
            f32x4 acc0 = {0.f, 0.f, 0.f, 0.f};

            #pragma unroll
            for (int hh = 0; hh < 4; ++hh) {
                const half8 a  = *(const half8*)(&x1h[l * XPH + hh * 32 + q * 8]); // broadcast
                const half8 bq = X2f[hh];
                const half8 Ap = a * bq;
                const half8 Ad = habs8(a - bq);
                acc0 = __builtin_amdgcn_mfma_f32_16x16x32_f16(Ap, Bf[hh],      acc0, 0, 0, 0);
                acc0 = __builtin_amdgcn_mfma_f32_16x16x32_f16(Ad, Bf[4 + hh],  acc0, 0, 0, 0);
                acc0 = __builtin_amdgcn_mfma_f32_16x16x32_f16(a,  Bf[8 + hh],  acc0, 0, 0, 0);
                acc0 = __builtin_amdgcn_mfma_f32_16x16x32_f16(bq, Bf[12 + hh], acc0, 0, 0, 0);
            }

            const int lg = l0 + l;
            if (cok) {
                #pragma unroll
                for (int r = 0; r < 4; ++r) {
                    const int mg = m0 + wv * 16 + q * 4 + r;
                    out[(((size_t)b * LL + lg) * LL + mg) * CC + cg] = acc0[r] + bt;
                }
            }
        }
    }
}

extern "C" void kernel_launch(void* const* d_in, const int* in_sizes, int n_in,
                              void* d_out, int out_size, void* d_ws, size_t ws_size,
                              hipStream_t stream) {
    const float* x1   = (const float*)d_in[0];
    const float* x2   = (const float*)d_in[1];
    const float* W    = (const float*)d_in[2];
    const float* bias = (const float*)d_in[3];
    float* out = (float*)d_out;
    _Float16* wsWf = (_Float16*)d_ws;

    wpack_kernel<<<8, 256, 0, stream>>>(W, wsWf);

    dim3 grid(LL / MTILE, LL / LPB, BB);    // (8, 64, 2) = 1024 blocks
    biaffine_fused<<<grid, 256, 0, stream>>>(x1, x2, wsWf, bias, out);
}

// Round 8
// 102.142 us; speedup vs baseline: 3.0575x; 3.0575x over previous
//
#include <hip/hip_runtime.h>
#include <hip/hip_bf16.h>
#include <math.h>

// (B, L, H, C) = (2, 512, 128, 25)
#define BB 2
#define LL 512
#define HH 128
#define CC 25
#define W4H (4*HH)

typedef __attribute__((ext_vector_type(4))) float    f32x4;
typedef __attribute__((ext_vector_type(8))) _Float16 half8;
typedef __attribute__((ext_vector_type(2))) _Float16 half2t;
typedef __attribute__((ext_vector_type(4))) unsigned uint4v;

#define MTILE 64    // m rows per block (4 waves x 16)
#define LPB   8     // l rows per block
#define XPH   136   // f16 LDS pitch in halves (272 B rows)

static __device__ __forceinline__ half8 habs8(half8 x) {
    uint4v u = __builtin_bit_cast(uint4v, x);
    u &= 0x7FFF7FFFu;
    return __builtin_bit_cast(half8, u);
}
static __device__ __forceinline__ half2t pkrtz(float a, float b) {
    return __builtin_bit_cast(half2t, __builtin_amdgcn_cvt_pkrtz(a, b));
}
union H4 { half2t h2[2]; unsigned long long u64; };
union H8 { half2t h2[4]; uint4v u4; half8 h8; };

// Features per (l,m): f[k], k in [0,512):
//   k<128: x1*x2 (W3) | 128<=k<256: |x1-x2| (W4) | 256<=k<384: x1 (W1) | else: x2 (W2)
// W column for feature k: (k+256) & 511.
// ws holds W fragments f16, fragment-linear: frag fid = (kk*2 + t)*64 + lane, 8 halves each.

// One-time W pack: 2048 fragments, 8 blocks x 256 threads, one frag per thread.
__global__ __launch_bounds__(256)
void wpack_kernel(const float* __restrict__ W, _Float16* __restrict__ wsWf)
{
    const int fid = blockIdx.x * 256 + threadIdx.x;   // 0..2047
    const int ln  = fid & 63;
    const int t   = (fid >> 6) & 1;
    const int kk  = fid >> 7;                          // 0..15
    const int c   = (ln & 15) + 16 * t;
    const int k0  = kk * 32 + ((ln >> 4) << 3);
    const int wc  = (k0 + 256) & 511;
    H8 h; h.u4 = (uint4v){0u, 0u, 0u, 0u};
    if (c < CC) {
        const f32x4 v0 = *(const f32x4*)(W + (size_t)c * W4H + wc);
        const f32x4 v1 = *(const f32x4*)(W + (size_t)c * W4H + wc + 4);
        h.h2[0] = pkrtz(v0[0], v0[1]);
        h.h2[1] = pkrtz(v0[2], v0[3]);
        h.h2[2] = pkrtz(v1[0], v1[1]);
        h.h2[3] = pkrtz(v1[2], v1[3]);
    }
    *(uint4v*)(wsWf + (size_t)fid * 8) = h.u4;        // contiguous 16B stores
}

__global__ __launch_bounds__(256)
void biaffine_fused(const float* __restrict__ x1, const float* __restrict__ x2,
                    const _Float16* __restrict__ wsWf, const float* __restrict__ bias,
                    float* __restrict__ out)
{
    __shared__ __align__(16) _Float16 x2h[MTILE * XPH];     // 17408 B
    __shared__ __align__(16) _Float16 x1h[LPB * XPH];       //  2176 B

    const int tid = threadIdx.x;
    const int b   = blockIdx.z;
    const int l0  = blockIdx.y * LPB;
    const int m0  = blockIdx.x * MTILE;

    const int lane = tid & 63;
    const int wv   = tid >> 6;      // wave 0..3
    const int q    = lane >> 4;     // k-group 0..3
    const int cn   = lane & 15;     // A-row (m) for frags; D-col (c) for output

    // ---- stage x2 tile (64x128) and x1 rows (8x128), f32 -> f16 ----
    {
        const float* sx2 = x2 + ((size_t)b * LL + m0) * HH;
        #pragma unroll
        for (int i = 0; i < 8; ++i) {
            const int idx = i * 256 + tid;
            const int r   = idx >> 5;
            const int c4  = idx & 31;
            const f32x4 v = *(const f32x4*)(sx2 + r * HH + c4 * 4);
            H4 h;
            h.h2[0] = pkrtz(v[0], v[1]);
            h.h2[1] = pkrtz(v[2], v[3]);
            *(unsigned long long*)(&x2h[r * XPH + c4 * 4]) = h.u64;
        }
        const float* sx1 = x1 + ((size_t)b * LL + l0) * HH;
        const int r  = tid >> 5;
        const int c4 = tid & 31;
        const f32x4 v = *(const f32x4*)(sx1 + r * HH + c4 * 4);
        H4 h;
        h.h2[0] = pkrtz(v[0], v[1]);
        h.h2[1] = pkrtz(v[2], v[3]);
        *(unsigned long long*)(&x1h[r * XPH + c4 * 4]) = h.u64;
    }
    __syncthreads();

    // ---- register-cache this lane's x2 fragments ----
    const int mrowA = wv * 16 + cn;
    half8 X2f[4];
    #pragma unroll
    for (int hh = 0; hh < 4; ++hh)
        X2f[hh] = *(const half8*)(&x2h[mrowA * XPH + hh * 32 + q * 8]);

    // ---- two c-tile passes: only 16 B-frags (64 VGPR) persistent at a time ----
    for (int t = 0; t < 2; ++t) {
        half8 Bf[16];
        #pragma unroll
        for (int kk = 0; kk < 16; ++kk)
            Bf[kk] = *(const half8*)(wsWf + ((size_t)(kk * 2 + t) * 64 + lane) * 8);

        const int  cg   = cn + 16 * t;
        const bool cok  = (cg < CC);
        const float bt  = cok ? bias[cg] : 0.f;

        #pragma unroll
        for (int l = 0; l < LPB; ++l) {
            f32x4 acc0 = {0.f, 0.f, 0.f, 0.f};

            #pragma unroll
            for (int hh = 0; hh < 4; ++hh) {
                const half8 a  = *(const half8*)(&x1h[l * XPH + hh * 32 + q * 8]); // broadcast
                const half8 bq = X2f[hh];
                const half8 Ap = a * bq;
                const half8 Ad = habs8(a - bq);
                acc0 = __builtin_amdgcn_mfma_f32_16x16x32_f16(Ap, Bf[hh],      acc0, 0, 0, 0);
                acc0 = __builtin_amdgcn_mfma_f32_16x16x32_f16(Ad, Bf[4 + hh],  acc0, 0, 0, 0);
                acc0 = __builtin_amdgcn_mfma_f32_16x16x32_f16(a,  Bf[8 + hh],  acc0, 0, 0, 0);
                acc0 = __builtin_amdgcn_mfma_f32_16x16x32_f16(bq, Bf[12 + hh], acc0, 0, 0, 0);
            }

            const int lg = l0 + l;
            if (cok) {
                float* obase = out + (((size_t)b * LL + lg) * LL + (m0 + wv * 16 + q * 4)) * CC + cg;
                #pragma unroll
                for (int r = 0; r < 4; ++r) {
                    obase[(size_t)r * CC] = acc0[r] + bt;
                }
            }
        }
    }
}

extern "C" void kernel_launch(void* const* d_in, const int* in_sizes, int n_in,
                              void* d_out, int out_size, void* d_ws, size_t ws_size,
                              hipStream_t stream) {
    const float* x1   = (const float*)d_in[0];
    const float* x2   = (const float*)d_in[1];
    const float* W    = (const float*)d_in[2];
    const float* bias = (const float*)d_in[3];
    float* out = (float*)d_out;
    _Float16* wsWf = (_Float16*)d_ws;

    wpack_kernel<<<8, 256, 0, stream>>>(W, wsWf);

    dim3 grid(LL / MTILE, LL / LPB, BB);    // (8, 64, 2) = 1024 blocks
    biaffine_fused<<<grid, 256, 0, stream>>>(x1, x2, wsWf, bias, out);
}